// Round 1
// baseline (555.546 us; speedup 1.0000x reference)
//
#include <hip/hip_runtime.h>

// ViterbiLoss (CRF forward) on MI355X.
// B=128, T=256, K=48 tags. One block per batch element; 4 waves; wave w owns
// output columns j in [12w, 12w+12); lane quad slot qq owns i-chunk [12qq,12qq+12).
// Register-prefetched feature columns (depth 4), s-vector ping-pong in LDS,
// one raw s_barrier per step (no vmcnt drain -> loads stay in flight).

#define NB 128
#define NT 256
#define NK 48
#define NKK (NK * NK)          // 2304
#define TAG_START 46
#define TAG_STOP 47
#define PDEPTH 4

__global__ __launch_bounds__(256, 1)
void viterbi_loss_kernel(const float* __restrict__ feats,
                         const int* __restrict__ targets,
                         const int* __restrict__ lengths,
                         float* __restrict__ out)
{
    const int b    = blockIdx.x;
    const int tid  = threadIdx.x;
    const int len  = lengths[b];            // 1..256
    const int last = len - 1;
    const float* __restrict__ fb = feats + (size_t)b * (NT * NKK);

    __shared__ float sbuf[2][NK];           // ping-pong score vector
    __shared__ float gred[4];               // per-wave gold partials

    // ---- gold score: thread tid handles timestep t = tid ----
    float g = 0.f;
    if (tid < len) {
        g = fb[(size_t)tid * NKK + targets[b * NT + tid]];
    }
    #pragma unroll
    for (int o = 32; o; o >>= 1) g += __shfl_down(g, o, 64);
    if ((tid & 63) == 0) gred[tid >> 6] = g;

    // ---- init: s_0 = feats[b, 0, START, :] ----
    if (tid < NK) sbuf[0][tid] = fb[TAG_START * NK + tid];

    __syncthreads();   // full barrier once before the pipeline starts

    const int lane = tid & 63;
    const int w    = tid >> 6;              // wave id -> j block
    const int jj   = lane >> 2;             // 0..15 (active < 12)
    const int qq   = lane & 3;              // i-chunk
    const int j    = w * 12 + jj;
    const bool act = (jj < 12);
    const int ib   = qq * 12;

    // this lane's column pointer: fb + t*NKK + (ib+k)*NK + j
    const float* cb = fb + ib * NK + j;

    // ---- register prefetch pipeline: pre[d] holds tile t+d ----
    float pre[PDEPTH][12];
    if (act) {
        #pragma unroll
        for (int d = 0; d < PDEPTH; ++d) {
            int tp = d + 1; if (tp > last) tp = last;   // clamp (values unused)
            const float* p = cb + tp * NKK;
            #pragma unroll
            for (int k = 0; k < 12; ++k) pre[d][k] = p[k * NK];
        }
    }

    float c = 0.f;   // running log-offset (uniform across all lanes)

    for (int t = 1; t < len; ++t) {
        // LDS-only barrier: do NOT drain vmcnt (keep prefetch loads in flight)
        asm volatile("s_waitcnt lgkmcnt(0)\n\ts_barrier" ::: "memory");

        // read previous scores (3x ds_read_b128, 4-address multicast)
        const float* sc = sbuf[(t + 1) & 1];
        float sv[12];
        #pragma unroll
        for (int k = 0; k < 12; ++k) sv[k] = sc[ib + k];

        // periodic renormalization, folded into the read phase
        if (((t - 1) & 3) == 0) {
            float m = sv[0];
            #pragma unroll
            for (int k = 1; k < 12; ++k) m = fmaxf(m, sv[k]);
            m = fmaxf(m, __shfl_xor(m, 1, 64));
            m = fmaxf(m, __shfl_xor(m, 2, 64));   // max over all 48 (wave-uniform)
            c += m;
            #pragma unroll
            for (int k = 0; k < 12; ++k) sv[k] -= m;
        }

        // partial sum over this lane's 12 i's
        float acc = 0.f;
        #pragma unroll
        for (int k = 0; k < 12; ++k) acc += __expf(pre[0][k] + sv[k]);

        // quad reduce -> full 48-term sum in every quad lane
        acc += __shfl_xor(acc, 1, 64);
        acc += __shfl_xor(acc, 2, 64);

        if (act && qq == 0) sbuf[t & 1][j] = __logf(acc);

        // rotate prefetch registers and issue loads for tile t+PDEPTH
        #pragma unroll
        for (int d = 0; d < PDEPTH - 1; ++d) {
            #pragma unroll
            for (int k = 0; k < 12; ++k) pre[d][k] = pre[d + 1][k];
        }
        int tp = t + PDEPTH; if (tp > last) tp = last;
        if (act) {
            const float* p = cb + tp * NKK;
            #pragma unroll
            for (int k = 0; k < 12; ++k) pre[PDEPTH - 1][k] = p[k * NK];
        }
    }

    __syncthreads();   // final: make last sbuf write visible (vmcnt drain harmless)

    if (tid == 0) {
        float res = sbuf[last & 1][TAG_STOP] + c
                  - (gred[0] + gred[1] + gred[2] + gred[3]);
        atomicAdd(out, res);
    }
}

extern "C" void kernel_launch(void* const* d_in, const int* in_sizes, int n_in,
                              void* d_out, int out_size, void* d_ws, size_t ws_size,
                              hipStream_t stream) {
    const float* feats   = (const float*)d_in[0];
    const int*   targets = (const int*)d_in[1];
    const int*   lengths = (const int*)d_in[2];
    float*       out     = (float*)d_out;

    hipMemsetAsync(out, 0, sizeof(float), stream);
    viterbi_loss_kernel<<<dim3(NB), dim3(NT), 0, stream>>>(feats, targets, lengths, out);
}

// Round 2
// 484.297 us; speedup vs baseline: 1.1471x; 1.1471x over previous
//
#include <hip/hip_runtime.h>

// ViterbiLoss (CRF forward-scan) on MI355X — v2.
// One block per batch (128 blocks, 256 thr = 4 waves). Wave w owns output
// columns j in [12w,12w+12); quad slot qq owns i-chunk [12qq,12qq+12).
// Feature tiles (48x48 f32) staged through a 4-slot LDS ring:
//   global float4 (coalesced) -> named regs (2 alternating sets, 2-iter slack)
//   -> ds_write_b128 (rows padded to 52 floats: conflict-free compute reads,
//      16B-aligned row starts).
// One raw `s_waitcnt lgkmcnt(0); s_barrier` per step — no vmcnt drain, so
// prefetch loads stay in flight across barriers. NO indexed local arrays
// (R1 post-mortem: pre[4][12] was spilled to scratch -> 2400 cyc/step).

#define NB 128
#define NT 256
#define NK 48
#define NKK (NK * NK)          // 2304
#define TAG_START 46
#define TAG_STOP 47
#define LROW 52                // padded LDS row stride (floats); 52*4=208 B, 16B aligned
#define TSZ (NK * LROW)        // 2496 floats per tile

#define STEP_BARRIER() asm volatile("s_waitcnt lgkmcnt(0)\n\ts_barrier" ::: "memory")

__global__ __launch_bounds__(256, 1)
void viterbi_loss_kernel(const float* __restrict__ feats,
                         const int* __restrict__ targets,
                         const int* __restrict__ lengths,
                         float* __restrict__ out)
{
    const int b    = blockIdx.x;
    const int tid  = threadIdx.x;
    const int len  = lengths[b];            // 1..256 (block-uniform)
    const int last = len - 1;
    const float* __restrict__ fb = feats + (size_t)b * (NT * NKK);

    __shared__ float tiles[4][TSZ];         // ring of staged feature tiles (~39 KB)
    __shared__ float sbuf[2][NK];           // ping-pong score vector
    __shared__ float gred[4];               // per-wave gold partials

    // ---- gold score: thread tid handles timestep t = tid ----
    float g = 0.f;
    if (tid < len) g = fb[(size_t)tid * NKK + targets[b * NT + tid]];
    #pragma unroll
    for (int o = 32; o; o >>= 1) g += __shfl_down(g, o, 64);
    if ((tid & 63) == 0) gred[tid >> 6] = g;

    // ---- init: s_0 = feats[b, 0, START, :] ----
    if (tid < NK) sbuf[0][tid] = fb[TAG_START * NK + tid];

    // ---- staging geometry: tile = 576 float4; thread handles e0,e1(,e2) ----
    const int e0 = tid, e1 = tid + 256, e2 = tid + 512;
    const int o0 = (e0 / 12) * 13 + (e0 % 12);   // LDS float4 slot (row stride 13 f4)
    const int o1 = (e1 / 12) * 13 + (e1 % 12);
    const int o2 = (e2 / 12) * 13 + (e2 % 12);
    const bool has2 = (tid < 64);                // 576 - 512

    // ---- compute geometry ----
    const int lane = tid & 63;
    const int w    = tid >> 6;
    const int jj   = lane >> 2;             // 0..15 (active < 12)
    const int qq   = lane & 3;
    const int j    = w * 12 + jj;
    const bool act = (jj < 12);
    const int ib   = qq * 12;

    // ---- prologue: stage tiles 1,2 -> slots 1,2; preload tile3->A, tile4->B ----
    float4 rA0, rA1, rA2, rB0, rB1, rB2;
    {
        const int t1 = (1 > last) ? last : 1;
        const int t2 = (2 > last) ? last : 2;
        const int t3 = (3 > last) ? last : 3;
        const int t4 = (4 > last) ? last : 4;
        const float4* p1 = (const float4*)(fb + (size_t)t1 * NKK);
        const float4* p2 = (const float4*)(fb + (size_t)t2 * NKK);
        float4 x0 = p1[e0], x1 = p1[e1], x2;
        float4 y0 = p2[e0], y1 = p2[e1], y2;
        if (has2) { x2 = p1[e2]; y2 = p2[e2]; }
        const float4* p3 = (const float4*)(fb + (size_t)t3 * NKK);
        const float4* p4 = (const float4*)(fb + (size_t)t4 * NKK);
        rA0 = p3[e0]; rA1 = p3[e1];
        rB0 = p4[e0]; rB1 = p4[e1];
        if (has2) { rA2 = p3[e2]; rB2 = p4[e2]; }
        float4* d1 = (float4*)tiles[1];
        float4* d2 = (float4*)tiles[2];
        d1[o0] = x0; d1[o1] = x1;
        d2[o0] = y0; d2[o1] = y1;
        if (has2) { d1[o2] = x2; d2[o2] = y2; }
    }
    STEP_BARRIER();

    float c = 0.f;   // running log-offset (uniform)

    auto step = [&](int t, float4& r0, float4& r1, float4& r2) {
        // commit tile t+2 (in regs, loaded 2 iters ago) into slot (t+2)&3
        float4* dst = (float4*)tiles[(t + 2) & 3];
        dst[o0] = r0; dst[o1] = r1;
        if (has2) dst[o2] = r2;

        // issue coalesced loads for tile t+4 (2-iteration slack)
        {
            int tp = t + 4; if (tp > last) tp = last;
            const float4* src = (const float4*)(fb + (size_t)tp * NKK);
            r0 = src[e0]; r1 = src[e1];
            if (has2) r2 = src[e2];
        }

        // read previous scores (3x ds_read_b128, 4 distinct banks -> clean)
        const float* sc = sbuf[(t + 1) & 1];
        const float4* scv = (const float4*)(sc + ib);
        float4 s0 = scv[0], s1 = scv[1], s2 = scv[2];

        // periodic renormalization (quad max == max over all 48, uniform)
        if (((t - 1) & 3) == 0) {
            float m = fmaxf(fmaxf(fmaxf(s0.x, s0.y), fmaxf(s0.z, s0.w)),
                            fmaxf(fmaxf(s1.x, s1.y), fmaxf(s1.z, s1.w)));
            m = fmaxf(m, fmaxf(fmaxf(s2.x, s2.y), fmaxf(s2.z, s2.w)));
            m = fmaxf(m, __shfl_xor(m, 1, 64));
            m = fmaxf(m, __shfl_xor(m, 2, 64));
            c += m;
            s0.x -= m; s0.y -= m; s0.z -= m; s0.w -= m;
            s1.x -= m; s1.y -= m; s1.z -= m; s1.w -= m;
            s2.x -= m; s2.y -= m; s2.z -= m; s2.w -= m;
        }

        // 12 exp + tree sum; LDS reads stride 52 -> 2-way conflicts (free)
        const float* tp0 = tiles[t & 3] + ib * LROW + j;
        float acc =
            (((__expf(tp0[0*LROW]  + s0.x) + __expf(tp0[1*LROW]  + s0.y)) +
              (__expf(tp0[2*LROW]  + s0.z) + __expf(tp0[3*LROW]  + s0.w))) +
             ((__expf(tp0[4*LROW]  + s1.x) + __expf(tp0[5*LROW]  + s1.y)) +
              (__expf(tp0[6*LROW]  + s1.z) + __expf(tp0[7*LROW]  + s1.w)))) +
            (((__expf(tp0[8*LROW]  + s2.x) + __expf(tp0[9*LROW]  + s2.y)) +
              (__expf(tp0[10*LROW] + s2.z) + __expf(tp0[11*LROW] + s2.w))));

        // quad reduce -> 48-term sum
        acc += __shfl_xor(acc, 1, 64);
        acc += __shfl_xor(acc, 2, 64);
        if (act && qq == 0) sbuf[t & 1][j] = __logf(acc);

        STEP_BARRIER();
    };

    int t = 1;
    while (t < len) {
        step(t, rA0, rA1, rA2); ++t;
        if (t >= len) break;
        step(t, rB0, rB1, rB2); ++t;
    }

    STEP_BARRIER();   // make final sbuf/gred visible to tid 0

    if (tid == 0) {
        float res = sbuf[last & 1][TAG_STOP] + c
                  - (gred[0] + gred[1] + gred[2] + gred[3]);
        atomicAdd(out, res);
    }
}

extern "C" void kernel_launch(void* const* d_in, const int* in_sizes, int n_in,
                              void* d_out, int out_size, void* d_ws, size_t ws_size,
                              hipStream_t stream) {
    const float* feats   = (const float*)d_in[0];
    const int*   targets = (const int*)d_in[1];
    const int*   lengths = (const int*)d_in[2];
    float*       out     = (float*)d_out;

    hipMemsetAsync(out, 0, sizeof(float), stream);
    viterbi_loss_kernel<<<dim3(NB), dim3(NT), 0, stream>>>(feats, targets, lengths, out);
}

// Round 3
// 409.558 us; speedup vs baseline: 1.3565x; 1.1825x over previous
//
#include <hip/hip_runtime.h>

// ViterbiLoss (CRF forward) on MI355X — v3.
// Key structure: meet-in-the-middle split. For each batch b with last=len-1:
//   forward  chain: s_t[j] = lse_i(M_t[i,j] + s_{t-1}[i]),  t = 1..m        (m = last/2)
//   backward chain: g_t[i] = lse_j(M_{t+1}[i,j] + g_{t+1}[j]), t = last-2..m,
//                   init g_{last-1}[i] = M_last[i,STOP]
//   result_b = lse_k(s_m[k] + g_m[k]);  total = sum_b result_b - gold.
// 256 blocks = (batch, dir), each chain <= 127 serial steps (2x shorter than v2).
// Features NEVER touch LDS: each lane keeps its 12 terms in NAMED registers,
// double-buffered 2 steps ahead (R1 lesson: indexed local arrays spill to
// scratch; R2 lesson: LDS tile staging costs ~600 DS-pipe cyc/step).
// LDS carries only the 48-float score vector; one raw lgkmcnt barrier/step.

#define NB 128
#define NT 256
#define NK 48
#define NKK (NK * NK)          // 2304
#define TAG_START 46
#define TAG_STOP 47

#define STEP_BARRIER() asm volatile("s_waitcnt lgkmcnt(0)\n\ts_barrier" ::: "memory")

#define LD12(v, p, ST) \
  v##0 = (p)[0*(ST)];  v##1 = (p)[1*(ST)];  v##2  = (p)[2*(ST)];  v##3  = (p)[3*(ST)]; \
  v##4 = (p)[4*(ST)];  v##5 = (p)[5*(ST)];  v##6  = (p)[6*(ST)];  v##7  = (p)[7*(ST)]; \
  v##8 = (p)[8*(ST)];  v##9 = (p)[9*(ST)];  v##10 = (p)[10*(ST)]; v##11 = (p)[11*(ST)];

#define STEPB(v, ST) { \
  const float* sc_ = &sv[(u + 1) & 1][rb]; \
  float4 s0 = *(const float4*)(sc_);     \
  float4 s1 = *(const float4*)(sc_ + 4); \
  float4 s2 = *(const float4*)(sc_ + 8); \
  if (((u - 1) & 3) == 0) { \
    float mm = fmaxf(fmaxf(fmaxf(s0.x,s0.y),fmaxf(s0.z,s0.w)), \
                     fmaxf(fmaxf(s1.x,s1.y),fmaxf(s1.z,s1.w))); \
    mm = fmaxf(mm, fmaxf(fmaxf(s2.x,s2.y),fmaxf(s2.z,s2.w))); \
    mm = fmaxf(mm, __shfl_xor(mm, 1, 64)); \
    mm = fmaxf(mm, __shfl_xor(mm, 2, 64)); \
    c += mm; \
    s0.x-=mm; s0.y-=mm; s0.z-=mm; s0.w-=mm; \
    s1.x-=mm; s1.y-=mm; s1.z-=mm; s1.w-=mm; \
    s2.x-=mm; s2.y-=mm; s2.z-=mm; s2.w-=mm; \
  } \
  float acc = (((__expf(v##0 + s0.x) + __expf(v##1 + s0.y)) + \
                (__expf(v##2 + s0.z) + __expf(v##3 + s0.w))) + \
               ((__expf(v##4 + s1.x) + __expf(v##5 + s1.y)) + \
                (__expf(v##6 + s1.z) + __expf(v##7 + s1.w)))) + \
              ((__expf(v##8 + s2.x) + __expf(v##9 + s2.y)) + \
               (__expf(v##10 + s2.z) + __expf(v##11 + s2.w))); \
  acc += __shfl_xor(acc, 1, 64); \
  acc += __shfl_xor(acc, 2, 64); \
  if (store) sv[u & 1][oo] = __logf(acc); \
  { int up_ = u + 2; if (up_ > nsteps) up_ = nsteps; \
    const float* p_ = basep + (long)up_ * dstep; LD12(v, p_, ST) } \
  STEP_BARRIER(); \
}

#define CHAIN(ST) { \
  float a0,a1,a2,a3,a4,a5,a6,a7,a8,a9,a10,a11; \
  float b0,b1,b2,b3,b4,b5,b6,b7,b8,b9,b10,b11; \
  { const float* p_ = basep + dstep; LD12(a, p_, ST) } \
  { int up_ = (2 > nsteps) ? nsteps : 2; \
    const float* p_ = basep + (long)up_ * dstep; LD12(b, p_, ST) } \
  __syncthreads(); \
  int u = 1; \
  for (;;) { \
    STEPB(a, ST) \
    if (++u > nsteps) break; \
    STEPB(b, ST) \
    if (++u > nsteps) break; \
  } \
}

__global__ __launch_bounds__(256, 1)
void viterbi_chain_kernel(const float* __restrict__ feats,
                          const int* __restrict__ targets,
                          const int* __restrict__ lengths,
                          float* __restrict__ out,
                          float* __restrict__ ws)
{
    const int bu  = blockIdx.x;
    const int b   = bu >> 1;
    const int dir = bu & 1;
    const int tid = threadIdx.x;
    const int len = lengths[b], last = len - 1, m = last >> 1;
    const float* __restrict__ fb = feats + (size_t)b * (NT * NKK);

    __shared__ float sv[2][NK];
    __shared__ float gred[4];

    // ---- gold slice: fwd owns t in [0,m], bwd owns t in [m+1,last] ----
    {
        int tg  = dir ? (m + 1 + tid) : tid;
        int tmx = dir ? last : m;
        float g = 0.f;
        if (tg <= tmx) g = fb[(size_t)tg * NKK + targets[b * NT + tg]];
        #pragma unroll
        for (int o = 32; o; o >>= 1) g += __shfl_down(g, o, 64);
        if ((tid & 63) == 0) gred[tid >> 6] = g;
    }

    // ---- chain init vector ----
    if (tid < NK) {
        float iv;
        if (dir) iv = (last == 0) ? ((tid == TAG_STOP) ? 0.f : -1e30f)
                                  : fb[(size_t)last * NKK + tid * NK + TAG_STOP];
        else     iv = fb[TAG_START * NK + tid];
        sv[0][tid] = iv;
    }

    const int lane = tid & 63, w = tid >> 6, qq = lane & 3, rb = qq * 12;
    const int oo   = w * 12 + (lane >> 2);           // output index (active < 48)
    const int ooc  = (oo < NK) ? oo : (NK - 1);      // clamped for addresses only
    const bool store = ((lane >> 2) < 12) && (qq == 0);

    int nsteps = dir ? (last - 1 - m) : m;
    if (nsteps < 0) nsteps = 0;

    float c = 0.f;
    if (nsteps > 0) {
        if (dir) {  // backward: lane reads row ooc, contiguous 12 -> dwordx4
            const float* basep = fb + (size_t)last * NKK + (size_t)ooc * NK + rb;
            const long dstep = -(long)NKK;
            CHAIN(1)
        } else {    // forward: lane reads column ooc, stride NK
            const float* basep = fb + (size_t)rb * NK + ooc;
            const long dstep = (long)NKK;
            CHAIN(NK)
        }
    } else {
        __syncthreads();
    }

    // ---- emit half-chain result: 48 floats + log-offset at [48] ----
    if (tid < NK) ws[(size_t)bu * 64 + tid] = sv[nsteps & 1][tid];
    if (tid == 0) {
        ws[(size_t)bu * 64 + 48] = c;
        atomicAdd(out, -(gred[0] + gred[1] + gred[2] + gred[3]));
    }
}

__global__ __launch_bounds__(64, 1)
void viterbi_combine_kernel(const float* __restrict__ ws,
                            float* __restrict__ out)
{
    const int b = blockIdx.x, lane = threadIdx.x;
    const float* f = ws + (size_t)(2 * b) * 64;
    const float* g = ws + (size_t)(2 * b + 1) * 64;
    float v = -3.0e38f;
    if (lane < NK) v = f[lane] + g[lane];
    float mm = v;
    #pragma unroll
    for (int o = 32; o; o >>= 1) mm = fmaxf(mm, __shfl_xor(mm, o, 64));
    float e = (lane < NK) ? __expf(v - mm) : 0.f;
    #pragma unroll
    for (int o = 32; o; o >>= 1) e += __shfl_xor(e, o, 64);
    if (lane == 0) atomicAdd(out, __logf(e) + mm + f[NK] + g[NK]);
}

extern "C" void kernel_launch(void* const* d_in, const int* in_sizes, int n_in,
                              void* d_out, int out_size, void* d_ws, size_t ws_size,
                              hipStream_t stream) {
    const float* feats   = (const float*)d_in[0];
    const int*   targets = (const int*)d_in[1];
    const int*   lengths = (const int*)d_in[2];
    float*       out     = (float*)d_out;
    float*       ws      = (float*)d_ws;

    hipMemsetAsync(out, 0, sizeof(float), stream);
    viterbi_chain_kernel<<<dim3(2 * NB), dim3(NT), 0, stream>>>(feats, targets, lengths, out, ws);
    viterbi_combine_kernel<<<dim3(NB), dim3(64), 0, stream>>>(ws, out);
}